// Round 1
// baseline (1260.151 us; speedup 1.0000x reference)
//
#include <hip/hip_runtime.h>
#include <hip/hip_bf16.h>
#include <float.h>

#define NS 32768
#define KER 256
#define TOUT 32513   // NS - KER + 1
#define NATOM 256
#define NSTEP 16
#define BATCH 8
#define NBLK 255     // ceil(TOUT/128)
#define SW(i) ((i) + ((i) >> 5))

__device__ __forceinline__ void cmax(float& babs, float& bsig, float& bidx,
                                     float oabs, float osig, float oidx) {
    if (oabs > babs || (oabs == babs && oidx < bidx)) {
        babs = oabs; bsig = osig; bidx = oidx;
    }
}

// Full correlation of residual(=x at step 0) with all 256 atoms + per-128-block abs-argmax.
// grid: (16 t-chunks of 2048, 8 atom-groups of 32, 8 batch), block 256
__global__ __launch_bounds__(256) void k_init_conv(const float* __restrict__ x,
                                                   const float* __restrict__ d,
                                                   float4* __restrict__ bm) {
    const int c  = blockIdx.x;
    const int og = blockIdx.y;
    const int b  = blockIdx.z;
    const int tid = threadIdx.x;
    __shared__ float rs[SW(2303) + 2];
    __shared__ float dt[32 * 256];
    const int base = c * 2048;
    for (int i = tid; i < 2304; i += 256) {
        int g = base + i;
        rs[SW(i)] = (g < NS) ? x[b * NS + g] : 0.0f;
    }
    {
        const float4* dsrc = reinterpret_cast<const float4*>(d + og * 32 * 256);
        float4* ddst = reinterpret_cast<float4*>(dt);
        for (int i = tid; i < 2048; i += 256) ddst[i] = dsrc[i];
    }
    __syncthreads();
    const int t0 = tid * 8;
    for (int o = 0; o < 32; ++o) {
        const float* dr = dt + o * 256;
        const int oglob = og * 32 + o;
        float acc[8];
#pragma unroll
        for (int j = 0; j < 8; ++j) acc[j] = 0.0f;
        float w[16];
#pragma unroll
        for (int j = 0; j < 16; ++j) w[j] = rs[SW(t0 + j)];
        for (int kk = 0; kk < 256; kk += 8) {
            float4 dva = *reinterpret_cast<const float4*>(dr + kk);
            float4 dvb = *reinterpret_cast<const float4*>(dr + kk + 4);
            float dv[8] = {dva.x, dva.y, dva.z, dva.w, dvb.x, dvb.y, dvb.z, dvb.w};
#pragma unroll
            for (int i = 0; i < 8; ++i) {
#pragma unroll
                for (int j = 0; j < 8; ++j)
                    acc[j] = fmaf(dv[i], w[i + j], acc[j]);
            }
#pragma unroll
            for (int j = 0; j < 8; ++j) w[j] = w[j + 8];
            if (kk + 8 < 256) {
#pragma unroll
                for (int j = 0; j < 8; ++j) w[j + 8] = rs[SW(t0 + kk + 16 + j)];
            }
        }
        // per-thread argmax over its 8 consecutive t (first-occurrence tie-break)
        float babs = -1.0f, bsig = 0.0f, bidx = 3.0e7f;
#pragma unroll
        for (int j = 0; j < 8; ++j) {
            int t = base + t0 + j;
            float a = fabsf(acc[j]);
            if (t < TOUT && a > babs) {
                babs = a; bsig = acc[j]; bidx = (float)(oglob * TOUT + t);
            }
        }
        // 16-lane group reduce (one group = one 128-t block)
#pragma unroll
        for (int m = 8; m >= 1; m >>= 1) {
            float oa = __shfl_xor(babs, m, 16);
            float os = __shfl_xor(bsig, m, 16);
            float oi = __shfl_xor(bidx, m, 16);
            cmax(babs, bsig, bidx, oa, os, oi);
        }
        if ((tid & 15) == 0) {
            int blk = c * 16 + (tid >> 4);
            if (blk < NBLK)
                bm[(b * NATOM + oglob) * NBLK + blk] = make_float4(babs, bsig, bidx, 0.0f);
        }
    }
}

// Per-atom (level-2) maxima over all blocks. grid (32 groups of 8 atoms, 8 b), block 256
__global__ __launch_bounds__(256) void k_lvl2(const float4* __restrict__ bm,
                                              float4* __restrict__ l2) {
    const int b = blockIdx.y;
    const int oglob = blockIdx.x * 8 + (threadIdx.x >> 5);
    const int lane = threadIdx.x & 31;
    const float4* row = bm + (b * NATOM + oglob) * NBLK;
    float babs = -1.0f, bsig = 0.0f, bidx = 3.0e7f;
    for (int i = lane; i < NBLK; i += 32) {
        float4 e = row[i];
        cmax(babs, bsig, bidx, e.x, e.y, e.z);
    }
#pragma unroll
    for (int m = 16; m >= 1; m >>= 1) {
        float oa = __shfl_xor(babs, m, 32);
        float os = __shfl_xor(bsig, m, 32);
        float oi = __shfl_xor(bidx, m, 32);
        cmax(babs, bsig, bidx, oa, os, oi);
    }
    if (lane == 0) l2[b * NATOM + oglob] = make_float4(babs, bsig, bidx, 0.0f);
}

// Global argmax over l2 + record step + subtract amp*d[atom] from residual.
// grid 8 (b), block 256
__global__ __launch_bounds__(256) void k_select(const float4* __restrict__ l2,
                                                const float* __restrict__ d,
                                                float* __restrict__ resid,
                                                int* __restrict__ pos_a,
                                                int* __restrict__ atom_a,
                                                float* __restrict__ amp_a,
                                                int step) {
    const int b = blockIdx.x;
    const int tid = threadIdx.x;
    __shared__ float4 red[4];
    __shared__ float4 bc;
    float4 e = l2[b * NATOM + tid];
    float babs = e.x, bsig = e.y, bidx = e.z;
#pragma unroll
    for (int m = 32; m >= 1; m >>= 1) {
        float oa = __shfl_xor(babs, m, 64);
        float os = __shfl_xor(bsig, m, 64);
        float oi = __shfl_xor(bidx, m, 64);
        cmax(babs, bsig, bidx, oa, os, oi);
    }
    if ((tid & 63) == 0) red[tid >> 6] = make_float4(babs, bsig, bidx, 0.0f);
    __syncthreads();
    if (tid == 0) {
        float4 r = red[0];
        for (int i = 1; i < 4; ++i) {
            float4 q = red[i];
            if (q.x > r.x || (q.x == r.x && q.z < r.z)) r = q;
        }
        int idx = (int)r.z;
        int atom = idx / TOUT;
        int pos = idx - atom * TOUT;
        pos_a[step * BATCH + b] = pos;
        atom_a[step * BATCH + b] = atom;
        amp_a[step * BATCH + b] = r.y;
        bc = make_float4(r.y, __int_as_float(pos), __int_as_float(atom), 0.0f);
    }
    __syncthreads();
    float amp = bc.x;
    int pos = __float_as_int(bc.y);
    int atom = __float_as_int(bc.z);
    float* rp = resid + b * NS + pos + tid;
    float dv = d[atom * KER + tid];
    *rp = __fsub_rn(*rp, __fmul_rn(amp, dv));
}

// Recompute correlation+blockmax only in the 511-wide window around previous pos,
// then refresh per-atom maxima. grid (32 groups of 8 atoms, 8 b), block 256
__global__ __launch_bounds__(256) void k_update(const float* __restrict__ resid,
                                                const float* __restrict__ d,
                                                float4* __restrict__ bm,
                                                float4* __restrict__ l2,
                                                const int* __restrict__ pos_a,
                                                int prev) {
    const int og = blockIdx.x;
    const int b  = blockIdx.y;
    const int tid = threadIdx.x;
    __shared__ float rs[896];
    __shared__ float dt[8 * 256];
    const int p = pos_a[prev * BATCH + b];
    int tlo = p - 255; if (tlo < 0) tlo = 0;
    int thi = p + 255; if (thi > TOUT - 1) thi = TOUT - 1;
    const int bs = tlo >> 7, be = thi >> 7;
    const int rbase = bs << 7;
    const int rlen = ((be - bs + 1) << 7) + 255;
    for (int i = tid; i < rlen; i += 256) {
        int g = rbase + i;
        rs[i] = (g < NS) ? resid[b * NS + g] : 0.0f;
    }
    {
        const float4* dsrc = reinterpret_cast<const float4*>(d + og * 8 * 256);
        float4* ddst = reinterpret_cast<float4*>(dt);
        for (int i = tid; i < 512; i += 256) ddst[i] = dsrc[i];
    }
    __syncthreads();
    const int wave = tid >> 6, lane = tid & 63;
    for (int blk = bs; blk <= be; ++blk) {
#pragma unroll
        for (int ai = 0; ai < 2; ++ai) {
            const int ol = wave * 2 + ai;
            const int oglob = og * 8 + ol;
            const float* dp = dt + ol * 256;
            const int t0 = (blk << 7) + lane * 2;
            const int li = t0 - rbase;
            float a0 = 0.0f, a1 = 0.0f;
            float r0 = rs[li], r1 = rs[li + 1];
#pragma unroll 4
            for (int k = 0; k < 256; ++k) {
                float dv = dp[k];
                a0 = fmaf(dv, r0, a0);
                a1 = fmaf(dv, r1, a1);
                r0 = r1; r1 = rs[li + k + 2];
            }
            float babs = -1.0f, bsig = 0.0f, bidx = 3.0e7f;
            if (t0 < TOUT) { babs = fabsf(a0); bsig = a0; bidx = (float)(oglob * TOUT + t0); }
            if (t0 + 1 < TOUT) {
                float a = fabsf(a1);
                if (a > babs) { babs = a; bsig = a1; bidx = (float)(oglob * TOUT + t0 + 1); }
            }
#pragma unroll
            for (int m = 32; m >= 1; m >>= 1) {
                float oa = __shfl_xor(babs, m, 64);
                float os = __shfl_xor(bsig, m, 64);
                float oi = __shfl_xor(bidx, m, 64);
                cmax(babs, bsig, bidx, oa, os, oi);
            }
            if (lane == 0)
                bm[(b * NATOM + oglob) * NBLK + blk] = make_float4(babs, bsig, bidx, 0.0f);
        }
    }
    __threadfence_block();
    __syncthreads();
    // refresh level-2 maxima for this wg's 8 atoms
    const int a8 = tid >> 5, lane32 = tid & 31;
    const int oglob = og * 8 + a8;
    const float4* row = bm + (b * NATOM + oglob) * NBLK;
    float babs = -1.0f, bsig = 0.0f, bidx = 3.0e7f;
    for (int i = lane32; i < NBLK; i += 32) {
        float4 e = row[i];
        cmax(babs, bsig, bidx, e.x, e.y, e.z);
    }
#pragma unroll
    for (int m = 16; m >= 1; m >>= 1) {
        float oa = __shfl_xor(babs, m, 32);
        float os = __shfl_xor(bsig, m, 32);
        float oi = __shfl_xor(bidx, m, 32);
        cmax(babs, bsig, bidx, oa, os, oi);
    }
    if (lane32 == 0) l2[b * NATOM + oglob] = make_float4(babs, bsig, bidx, 0.0f);
}

// Head: out[b,o,s] = br[o] + sum_c wr[o][c]*pa[c] + wr[o][128+c]*at[c]
// pa[c] = wpa[c][0]*posn + wpa[c][1]*amp + bpa[c]; at[c] = wat[c][atom] + bat[c]
// grid (16 steps, 8 b), block 128
__global__ __launch_bounds__(128) void k_head(const int* __restrict__ pos_a,
                                              const int* __restrict__ atom_a,
                                              const float* __restrict__ amp_a,
                                              const float* __restrict__ wpa,
                                              const float* __restrict__ bpa,
                                              const float* __restrict__ wat,
                                              const float* __restrict__ bat,
                                              const float* __restrict__ wr,
                                              const float* __restrict__ br,
                                              float* __restrict__ out) {
    const int s = blockIdx.x, b = blockIdx.y;
    const int o = threadIdx.x;
    const int pos = pos_a[s * BATCH + b];
    const int atom = atom_a[s * BATCH + b];
    const float amp = amp_a[s * BATCH + b];
    const float posn = (float)pos / 32513.0f;
    float sum = br[o];
    for (int c = 0; c < 128; ++c) {
        float pa = wpa[c * 2] * posn + wpa[c * 2 + 1] * amp + bpa[c];
        float at = wat[c * 256 + atom] + bat[c];
        sum += wr[o * 256 + c] * pa + wr[o * 256 + 128 + c] * at;
    }
    out[(b * 128 + o) * NSTEP + s] = sum;
}

extern "C" void kernel_launch(void* const* d_in, const int* in_sizes, int n_in,
                              void* d_out, int out_size, void* d_ws, size_t ws_size,
                              hipStream_t stream) {
    const float* x   = (const float*)d_in[0];
    const float* d   = (const float*)d_in[1];
    const float* wpa = (const float*)d_in[2];
    const float* bpa = (const float*)d_in[3];
    const float* wat = (const float*)d_in[4];
    const float* bat = (const float*)d_in[5];
    const float* wr  = (const float*)d_in[6];
    const float* br  = (const float*)d_in[7];
    float* out = (float*)d_out;

    char* ws = (char*)d_ws;
    float*  resid = (float*)ws;                                   // 1 MiB
    float4* bm    = (float4*)(ws + (1 << 20));                    // 8*256*255*16 = 8,355,840 B
    float4* l2    = (float4*)(ws + (1 << 20) + 8355840);          // 32 KiB
    int*    pos_a = (int*)(ws + (1 << 20) + 8355840 + 32768);
    int*    atom_a = pos_a + NSTEP * BATCH;
    float*  amp_a  = (float*)(atom_a + NSTEP * BATCH);

    hipMemcpyAsync(resid, x, BATCH * NS * sizeof(float), hipMemcpyDeviceToDevice, stream);
    k_init_conv<<<dim3(16, 8, 8), 256, 0, stream>>>(x, d, bm);
    k_lvl2<<<dim3(32, 8), 256, 0, stream>>>(bm, l2);
    k_select<<<dim3(8), 256, 0, stream>>>(l2, d, resid, pos_a, atom_a, amp_a, 0);
    for (int s = 1; s < NSTEP; ++s) {
        k_update<<<dim3(32, 8), 256, 0, stream>>>(resid, d, bm, l2, pos_a, s - 1);
        k_select<<<dim3(8), 256, 0, stream>>>(l2, d, resid, pos_a, atom_a, amp_a, s);
    }
    k_head<<<dim3(16, 8), 128, 0, stream>>>(pos_a, atom_a, amp_a, wpa, bpa, wat, bat, wr, br, out);
}